// Round 1
// baseline (907.728 us; speedup 1.0000x reference)
//
#include <hip/hip_runtime.h>
#include <hip/hip_bf16.h>

// out[m,n] = sum_r sum_k inp[r,m,k] * wgt[r,n,k]
// W=8, M=N=4096, K=1792 -> single GEMM M=N=4096, Ktot=14336, fp32 in/out,
// bf16 MFMA (absmax 7.8e-3 vs 3.39e-2 threshold).

#define Wsz 8
#define Mdim 4096
#define Ndim 4096
#define Kshard 1792
#define KTOT 14336
#define LDSBUF 32768   // one pipeline stage: A 16KB + B 16KB

typedef __attribute__((ext_vector_type(8))) short short8;
typedef __attribute__((ext_vector_type(4))) float f32x4;

__device__ __forceinline__ unsigned short f2bf(float x) {
    unsigned u = __builtin_bit_cast(unsigned, x);
    u = (u + 0x7FFFu + ((u >> 16) & 1u)) >> 16;   // RNE
    return (unsigned short)u;
}

// ---------------------------------------------------------------------------
// Convert+reshuffle, BOTH matrices in one launch:
//   src [8][4096][1792] f32 -> dst [4096][14336] bf16.
// Fully lane-dense: each instruction is 64 contiguous float4 loads / uint2
// stores (old version strided 16B loads at 32B pitch per instruction).
// blocks 0..28671 -> matrix 0, 28672..57343 -> matrix 1.
// Per block: 512 consecutive float4 (2 per thread, +256 apart).
// ---------------------------------------------------------------------------
__global__ void __launch_bounds__(256) cvt2_kernel(const float* __restrict__ s0,
                                                   const float* __restrict__ s1,
                                                   unsigned short* __restrict__ d0,
                                                   unsigned short* __restrict__ d1) {
    const unsigned BPM = (Wsz * Mdim * (Kshard / 4)) / 512;   // 28672
    unsigned b = blockIdx.x;
    const float* src;
    unsigned short* dst;
    if (b >= BPM) { src = s1; dst = d1; b -= BPM; }
    else          { src = s0; dst = d0; }
    const unsigned f0 = b * 512 + threadIdx.x;
#pragma unroll
    for (int i = 0; i < 2; ++i) {
        const unsigned f  = f0 + i * 256;           // float4 index, < 14,680,064
        const unsigned k4 = f % 448u;               // float4 within K-shard row
        const unsigned t  = f / 448u;               // (r,m)
        const unsigned m  = t & 4095u;
        const unsigned r  = t >> 12;
        const float4 v = ((const float4*)src)[f];
        uint2 o;
        o.x = (unsigned)f2bf(v.x) | ((unsigned)f2bf(v.y) << 16);
        o.y = (unsigned)f2bf(v.z) | ((unsigned)f2bf(v.w) << 16);
        ((uint2*)dst)[(size_t)m * (KTOT / 4) + r * (Kshard / 4) + k4] = o;
    }
}

// ---------------------------------------------------------------------------
// 256x256 tile GEMM, BK=32, 512 threads (8 waves as 4Mx2N, wave = 64x128).
// Depth-2 pipeline over 4 LDS buffers; counted s_waitcnt vmcnt(4) so prefetch
// loads stay in flight across barriers (unchanged, proven).
// NEW: each K-step split into two barrier-delimited phases with
// sched_barrier(0) pinning + s_setprio(1) around each 16-MFMA cluster
// (T3 fine phasing + T5, per m218b/m224: +18-35% on counted-vmcnt 256^2).
// Staging/swizzle/slot rotation identical to the previous verified kernel.
// ---------------------------------------------------------------------------
__global__ void __launch_bounds__(512, 2) gemm_bt(const unsigned short* __restrict__ A,
                                                  const unsigned short* __restrict__ B,
                                                  float* __restrict__ C) {
    extern __shared__ char smem[];   // 4 * LDSBUF = 128 KiB

    const int tid = threadIdx.x;
    const int w = tid >> 6, lane = tid & 63;
    const int l15 = lane & 15, quad = lane >> 4;
    const int wm = (w >> 1) * 64;    // wave M offset (0..192)
    const int wn = (w & 1) * 128;    // wave N offset (0/128)
    const long bm = (long)blockIdx.y * 256, bn = (long)blockIdx.x * 256;

    // --- staging decode: 512 lanes cover 512 of 1024 16B chunks per matrix;
    // each thread issues chunk g and g+512 (rows sr and sr+128).
    // LDS chunk g sits at byte g*16 (linear). Global k-chunk for (row r, col c)
    // is q = c ^ ((r>>1)&3)  -> measured 0 bank conflicts on fragment reads.
    const int chunk = w * 64 + lane;          // 0..511
    const int sr = chunk >> 2;                // 0..127
    const int sq = (chunk & 3) ^ ((sr >> 1) & 3);
    const unsigned short* aP0 = A + (size_t)(bm + sr) * KTOT + sq * 8;
    const unsigned short* aP1 = aP0 + (size_t)128 * KTOT;
    const unsigned short* bP0 = B + (size_t)(bn + sr) * KTOT + sq * 8;
    const unsigned short* bP1 = bP0 + (size_t)128 * KTOT;
    const int ldsW = w * 1024;                // wave-uniform LDS base offset

    // --- fragment read offsets (row stride 64B, swizzled 16B column)
    const int swz = (quad ^ ((l15 >> 1) & 3)) * 16;
    const int aoff = (wm + l15) * 64 + swz;
    const int boff = 16384 + (wn + l15) * 64 + swz;

    f32x4 acc[4][8] = {};

#define STAGE(bufbase, kt)                                                                              \
    do {                                                                                                \
        __builtin_amdgcn_global_load_lds((const __attribute__((address_space(1))) void*)(aP0 + (kt)),   \
            (__attribute__((address_space(3))) void*)(smem + (bufbase) + ldsW), 16, 0, 0);              \
        __builtin_amdgcn_global_load_lds((const __attribute__((address_space(1))) void*)(aP1 + (kt)),   \
            (__attribute__((address_space(3))) void*)(smem + (bufbase) + ldsW + 8192), 16, 0, 0);       \
        __builtin_amdgcn_global_load_lds((const __attribute__((address_space(1))) void*)(bP0 + (kt)),   \
            (__attribute__((address_space(3))) void*)(smem + (bufbase) + 16384 + ldsW), 16, 0, 0);      \
        __builtin_amdgcn_global_load_lds((const __attribute__((address_space(1))) void*)(bP1 + (kt)),   \
            (__attribute__((address_space(3))) void*)(smem + (bufbase) + 16384 + ldsW + 8192), 16, 0, 0);\
    } while (0)

    // One K-step = two phases:
    //  phase 1: af[0..3] + bf0[0..3] ds_reads, (stage next+2), barrier,
    //           setprio(1), 16 MFMA (n0-3), setprio(0)
    //  phase 2: bf1[0..3] ds_reads, barrier, setprio(1), 16 MFMA (n4-7),
    //           setprio(0), TAILASM (vmcnt(4)+barrier in steady state)
#define KSTEP(bufbase, DOSTAGE, stagebase, kt, TAILASM)                                  \
    do {                                                                                 \
        short8 af[4], bf0[4], bf1[4];                                                    \
        _Pragma("unroll") for (int i = 0; i < 4; ++i)                                    \
            af[i] = *(const short8*)(smem + (bufbase) + aoff + i * 1024);                \
        _Pragma("unroll") for (int i = 0; i < 4; ++i)                                    \
            bf0[i] = *(const short8*)(smem + (bufbase) + boff + i * 1024);               \
        if (DOSTAGE) STAGE(stagebase, kt);                                               \
        asm volatile("s_barrier" ::: "memory");                                          \
        __builtin_amdgcn_sched_barrier(0);                                               \
        __builtin_amdgcn_s_setprio(1);                                                   \
        _Pragma("unroll") for (int mi = 0; mi < 4; ++mi)                                 \
            _Pragma("unroll") for (int ni = 0; ni < 4; ++ni)                             \
                acc[mi][ni] = __builtin_amdgcn_mfma_f32_16x16x32_bf16(af[mi], bf0[ni],   \
                                                                      acc[mi][ni], 0, 0, 0); \
        __builtin_amdgcn_s_setprio(0);                                                   \
        _Pragma("unroll") for (int i = 0; i < 4; ++i)                                    \
            bf1[i] = *(const short8*)(smem + (bufbase) + boff + (4 + i) * 1024);         \
        asm volatile("s_barrier" ::: "memory");                                          \
        __builtin_amdgcn_sched_barrier(0);                                               \
        __builtin_amdgcn_s_setprio(1);                                                   \
        _Pragma("unroll") for (int mi = 0; mi < 4; ++mi)                                 \
            _Pragma("unroll") for (int ni = 0; ni < 4; ++ni)                             \
                acc[mi][ni + 4] = __builtin_amdgcn_mfma_f32_16x16x32_bf16(af[mi], bf1[ni], \
                                                                      acc[mi][ni + 4], 0, 0, 0); \
        __builtin_amdgcn_s_setprio(0);                                                   \
        asm volatile(TAILASM ::: "memory");                                              \
    } while (0)

#define TAIL4 "s_waitcnt vmcnt(4)\ns_barrier"
#define TAIL0 "s_waitcnt vmcnt(0)\ns_barrier"

    // prologue: stage buf0 (kt=0), buf1 (kt=32); ensure buf0 landed.
    STAGE(0, 0);
    STAGE(LDSBUF, 32);
    asm volatile(TAIL4 ::: "memory");

    long kt = 0;
    // 448 steps total; main loop covers 0..443 (111 x 4-unroll, static buf ids).
    // End-of-step vmcnt(4) forces stage(u-1) landed before step u+1 reads it
    // (identical guarantee chain to the previous kernel's top-of-step BAR4).
    for (int blk = 0; blk < 111; ++blk) {
#pragma unroll
        for (int u = 0; u < 4; ++u) {
            KSTEP(u * LDSBUF, true, ((u + 2) & 3) * LDSBUF, kt + 64, TAIL4);
            kt += 32;
        }
    }
    // tail: steps 444..447 (kt = 14208); last stages at 444 (k14272), 445 (k14304)
    KSTEP(0,          true,  2 * LDSBUF, kt + 64, TAIL4); kt += 32;   // 444
    KSTEP(LDSBUF,     true,  3 * LDSBUF, kt + 64, TAIL4); kt += 32;   // 445
    KSTEP(2 * LDSBUF, false, 0,          0,       TAIL0);             // 446
    KSTEP(3 * LDSBUF, false, 0,          0,       "");                // 447

#undef STAGE
#undef KSTEP
#undef TAIL4
#undef TAIL0

    // C/D layout (m89/m91): col = lane&15, row = quad*4 + reg
#pragma unroll
    for (int mi = 0; mi < 4; ++mi)
#pragma unroll
        for (int ni = 0; ni < 8; ++ni) {
            const long col = bn + wn + ni * 16 + l15;
#pragma unroll
            for (int r2 = 0; r2 < 4; ++r2) {
                const long row = bm + wm + mi * 16 + quad * 4 + r2;
                C[row * Ndim + col] = acc[mi][ni][r2];
            }
        }
}

// ---------------------------------------------------------------------------
// Fallback (ws too small): inline-convert 128x128 kernel, unchanged.
// ---------------------------------------------------------------------------
__global__ void __launch_bounds__(256) gemm_inline(const float* __restrict__ A,
                                                   const float* __restrict__ B,
                                                   float* __restrict__ C) {
    __shared__ short As[128 * 32];
    __shared__ short Bs[128 * 32];

    const int tid = threadIdx.x;
    const int w = tid >> 6, lane = tid & 63;
    const int bm = blockIdx.y * 128, bn = blockIdx.x * 128;
    const int wm = (w >> 1) * 64, wn = (w & 1) * 64;
    const int lane15 = lane & 15, quad = lane >> 4;

    const int srow = tid >> 3;
    const int skc  = (tid & 7) * 4;

    const char* a_rd = (const char*)As + ((size_t)(wm + lane15) * 32 + quad * 8) * 2;
    const char* b_rd = (const char*)Bs + ((size_t)(wn + lane15) * 32 + quad * 8) * 2;

    f32x4 acc[4][4] = {};
    long base = 0; int kloc = 0;

    for (int kt = 0; kt < KTOT; kt += 32) {
        const float* ap = A + base + kloc + (long)(bm + srow) * Kshard + skc;
        const float* bp = B + base + kloc + (long)(bn + srow) * Kshard + skc;
        float4 av[4], bv[4];
#pragma unroll
        for (int i = 0; i < 4; ++i) {
            av[i] = *(const float4*)(ap + (long)i * 32 * Kshard);
            bv[i] = *(const float4*)(bp + (long)i * 32 * Kshard);
        }
        __syncthreads();
#pragma unroll
        for (int i = 0; i < 4; ++i) {
            ushort4 oa, ob;
            oa.x = f2bf(av[i].x); oa.y = f2bf(av[i].y); oa.z = f2bf(av[i].z); oa.w = f2bf(av[i].w);
            ob.x = f2bf(bv[i].x); ob.y = f2bf(bv[i].y); ob.z = f2bf(bv[i].z); ob.w = f2bf(bv[i].w);
            *(ushort4*)((char*)As + ((size_t)(srow + i * 32) * 32 + skc) * 2) = oa;
            *(ushort4*)((char*)Bs + ((size_t)(srow + i * 32) * 32 + skc) * 2) = ob;
        }
        __syncthreads();

        short8 af[4], bfr[4];
#pragma unroll
        for (int i = 0; i < 4; ++i) {
            af[i]  = *(const short8*)(a_rd + (size_t)i * 16 * 64);
            bfr[i] = *(const short8*)(b_rd + (size_t)i * 16 * 64);
        }
#pragma unroll
        for (int mi = 0; mi < 4; ++mi)
#pragma unroll
            for (int ni = 0; ni < 4; ++ni)
                acc[mi][ni] = __builtin_amdgcn_mfma_f32_16x16x32_bf16(af[mi], bfr[ni], acc[mi][ni], 0, 0, 0);

        kloc += 32;
        if (kloc == Kshard) { kloc = 0; base += (long)Mdim * Kshard; }
    }

#pragma unroll
    for (int mi = 0; mi < 4; ++mi)
#pragma unroll
        for (int ni = 0; ni < 4; ++ni) {
            const int col = bn + wn + ni * 16 + lane15;
#pragma unroll
            for (int r2 = 0; r2 < 4; ++r2) {
                const int row = bm + wm + mi * 16 + quad * 4 + r2;
                C[(size_t)row * Ndim + col] = acc[mi][ni][r2];
            }
        }
}

extern "C" void kernel_launch(void* const* d_in, const int* in_sizes, int n_in,
                              void* d_out, int out_size, void* d_ws, size_t ws_size,
                              hipStream_t stream) {
    const float* inp = (const float*)d_in[0];   // [8][4096][1792] f32
    const float* wgt = (const float*)d_in[1];   // [8][4096][1792] f32
    float* out = (float*)d_out;                 // [4096][4096] f32

    const size_t one_mat = (size_t)Mdim * KTOT * 2;   // 117,440,512 B
    if (ws_size >= 2 * one_mat) {
        unsigned short* Abf = (unsigned short*)d_ws;
        unsigned short* Bbf = (unsigned short*)((char*)d_ws + one_mat);
        const int cvt_blocks = 2 * ((Wsz * Mdim * (Kshard / 4)) / 512);   // 57344
        cvt2_kernel<<<cvt_blocks, 256, 0, stream>>>(inp, wgt, Abf, Bbf);
        hipFuncSetAttribute(reinterpret_cast<const void*>(gemm_bt),
                            hipFuncAttributeMaxDynamicSharedMemorySize, 4 * LDSBUF);
        dim3 grid(Ndim / 256, Mdim / 256);
        gemm_bt<<<grid, 512, 4 * LDSBUF, stream>>>(Abf, Bbf, out);
    } else {
        dim3 grid(Ndim / 128, Mdim / 128);
        gemm_inline<<<grid, 256, 0, stream>>>(inp, wgt, out);
    }
}